// Round 3
// baseline (372.556 us; speedup 1.0000x reference)
//
#include <hip/hip_runtime.h>
#include <hip/hip_cooperative_groups.h>
#include <math.h>

namespace cg = cooperative_groups;

// Problem constants (fixed by reference)
constexpr int Bn = 4, Ln = 2048, DM = 512, NH = 8, DKv = 32, INNER = 256;
constexpr int TTOK = Bn * Ln;                              // 8192 tokens
constexpr size_t HEAD_ELEMS = (size_t)Bn * NH * Ln * DKv;  // 2,097,152 elems per Q/K/V

// Workspace layout (shorts):
//  [0,2M)   Qh bf16 [n,h,l,d]  (PRE-SCALED by log2(e)/sqrt(32))
//  [2M,4M)  Kh bf16 [n,h,l,d]
//  [4M,6M)  Vt bf16 [n,h,d,l]
//  [6M,8M)  O2b bf16 [tok][256]
//  [12.25M, +393216)  Wb bf16 (Wq|Wk|Wv)
//  [+131072]          Wfcb bf16

typedef short short8 __attribute__((ext_vector_type(8)));   // 8 bf16 (4 VGPRs)
typedef short short4v __attribute__((ext_vector_type(4)));  // 4 bf16 (2 VGPRs)
typedef float floatx4 __attribute__((ext_vector_type(4)));  // 16x16 MFMA C/D frag
typedef float floatx16 __attribute__((ext_vector_type(16))); // 32x32 MFMA C/D frag

constexpr size_t WB_OFF  = 12536832;                // shorts, 16B aligned
constexpr size_t WFCB_OFF = WB_OFF + 3 * 131072;

constexpr float C1 = 0.25505654f;  // log2(e)/sqrt(32), folded into Qh at projection

__device__ inline short f2bf(float x) {                     // RNE f32->bf16
  unsigned u = __builtin_bit_cast(unsigned, x);
  unsigned r = (u + 0x7FFFu + ((u >> 16) & 1u)) >> 16;
  return (short)r;
}

// ==================== MEGA KERNEL (cooperative, 4 phases) ====================
// grid 512 x 256 threads, >=2 blocks/CU co-resident (LDS 46KB -> 3/CU bound).
// Phase 0: weight cvt (1 float4/thread exactly covers 4x131072 elems)
// Phase 1: projection, 384 units of 64tok x 256col (blocks 384..511 idle)
// Phase 2: attention, 512 units (head,qblock), XCD-affine mapping
// Phase 3: fused FC+residual+LayerNorm, 512 units of 16 tokens
// grid.sync() between phases replaces kernel launches (removes 4 gaps and
// makes this one dispatch big enough to surface in rocprof top-5 WITH counters).
__global__ __launch_bounds__(256, 2) void mega_kernel(
    const float* __restrict__ q, const float* __restrict__ kin,
    const float* __restrict__ vin,
    const float* __restrict__ Wq, const float* __restrict__ Wk,
    const float* __restrict__ Wv, const float* __restrict__ Wfc,
    const float* __restrict__ bq, const float* __restrict__ bk,
    const float* __restrict__ bv, const float* __restrict__ bfc,
    const float* __restrict__ gamma, const float* __restrict__ beta,
    short* __restrict__ wsS, float* __restrict__ outp)
{
  cg::grid_group grid = cg::this_grid();
  const int u = blockIdx.x;
  const int tid = threadIdx.x;

  short* Wb   = wsS + WB_OFF;
  short* Wfcb = wsS + WFCB_OFF;
  short* O2b  = wsS + 3 * HEAD_ELEMS;

  __shared__ __align__(16) short smem[23040];   // 46.1 KB union for all phases

  // ---------------- phase 0: weight fp32->bf16 ----------------
  {
    const int z = u >> 7, xb = u & 127;
    const float* src = z == 0 ? Wq : (z == 1 ? Wk : (z == 2 ? Wv : Wfc));
    short* dst = z < 3 ? Wb + (size_t)z * 131072 : Wfcb;
    const int idx = (xb * 256 + tid) * 4;
    float4 x = *(const float4*)&src[idx];
    *(short4v*)&dst[idx] = (short4v){f2bf(x.x), f2bf(x.y), f2bf(x.z), f2bf(x.w)};
  }
  grid.sync();

  // ---------------- phase 1: projection (X read once) ----------------
  if (u < 384) {
    const int mat = u >> 7;
    const int t0 = (u & 127) * 64;
    const float* X    = mat == 0 ? q  : (mat == 1 ? kin : vin);
    const short* W    = Wb + (size_t)mat * 131072;
    const float* bias = mat == 0 ? bq : (mat == 1 ? bk : bv);
    short* outph = wsS + (size_t)mat * HEAD_ELEMS;

    const int col = tid & 15;
    const int quad = (tid & 63) >> 4;
    const int w = tid >> 6;

    short* Xs  = smem;
    short* Wsh = smem + 64 * 72;

    floatx4 acc[16];
#pragma unroll
    for (int nj = 0; nj < 16; ++nj) acc[nj] = (floatx4){0.f, 0.f, 0.f, 0.f};

    float4 xr[4];
    short8 wr[8];
    auto loadX = [&](int k0) {
#pragma unroll
      for (int j = 0; j < 4; ++j) {
        const int i = tid + j * 256, row = i >> 4, c4 = i & 15;
        xr[j] = *(const float4*)&X[(size_t)(t0 + row) * DM + k0 + c4 * 4];
      }
    };
    auto loadW = [&](int k0) {
#pragma unroll
      for (int j = 0; j < 8; ++j) {
        const int s = tid + j * 256, jrow = s >> 3, c8 = s & 7;
        const int wrow = ((jrow & 31) << 3) + (jrow >> 5);   // internal j -> W row
        wr[j] = *(const short8*)&W[(size_t)wrow * DM + k0 + c8 * 8];
      }
    };

    loadX(0);
    loadW(0);

    for (int kc = 0; kc < 8; ++kc) {
#pragma unroll
      for (int j = 0; j < 4; ++j) {
        const int i = tid + j * 256, row = i >> 4, c4 = i & 15;
        *(short4v*)&Xs[row * 72 + c4 * 4] =
            (short4v){f2bf(xr[j].x), f2bf(xr[j].y), f2bf(xr[j].z), f2bf(xr[j].w)};
      }
#pragma unroll
      for (int j = 0; j < 8; ++j) {
        const int s = tid + j * 256, jrow = s >> 3, c8 = s & 7;
        *(short8*)&Wsh[jrow * 72 + c8 * 8] = wr[j];
      }
      __syncthreads();
      if (kc < 7) {                       // prefetch next chunk while MFMAs run
        loadX((kc + 1) * 64);
        loadW((kc + 1) * 64);
      }
#pragma unroll
      for (int ks = 0; ks < 2; ++ks) {
        short8 a = *(const short8*)&Xs[(w * 16 + col) * 72 + ks * 32 + quad * 8];
#pragma unroll
        for (int nj = 0; nj < 16; ++nj) {
          short8 b = *(const short8*)&Wsh[(nj * 16 + col) * 72 + ks * 32 + quad * 8];
          acc[nj] = __builtin_amdgcn_mfma_f32_16x16x32_bf16(a, b, acc[nj], 0, 0, 0);
        }
      }
      __syncthreads();
    }

    short* Ct = smem;
    const int n = t0 >> 11, llb = t0 & (Ln - 1);

    if (mat < 2) {
#pragma unroll
      for (int nj = 0; nj < 16; ++nj) {
        const int j = nj * 16 + col;
        const int c = ((j & 31) << 3) + (j >> 5);
        const float bi = bias[c];
#pragma unroll
        for (int r = 0; r < 4; ++r) {
          float pv = acc[nj][r] + bi;
          if (mat == 0) pv *= C1;
          Ct[(w * 16 + quad * 4 + r) * 268 + j] = f2bf(pv);
        }
      }
      __syncthreads();
#pragma unroll
      for (int it = 0; it < 8; ++it) {
        const int cid = tid + it * 256;
        const int h = cid >> 8, tok = (cid >> 2) & 63, o = cid & 3;
        short8 val = *(const short8*)&Ct[tok * 268 + h * 32 + o * 8];
        *(short8*)&outph[((size_t)(n * NH + h) * Ln + llb + tok) * DKv + o * 8] = val;
      }
    } else {
#pragma unroll
      for (int nj = 0; nj < 16; ++nj) {
        const int j = nj * 16 + col;
        const int c = ((j & 31) << 3) + (j >> 5);
        const float bi = bias[c];
        short4v pk = (short4v){f2bf(acc[nj][0] + bi), f2bf(acc[nj][1] + bi),
                               f2bf(acc[nj][2] + bi), f2bf(acc[nj][3] + bi)};
        *(short4v*)&Ct[j * 72 + w * 16 + quad * 4] = pk;
      }
      __syncthreads();
#pragma unroll
      for (int it = 0; it < 8; ++it) {
        const int cid = tid + it * 256;
        const int j = cid >> 3, to = cid & 7;
        const int h = j >> 5, d = j & 31;
        short8 val = *(const short8*)&Ct[j * 72 + to * 8];
        *(short8*)&outph[((size_t)(n * NH + h) * DKv + d) * Ln + llb + to * 8] = val;
      }
    }
  }
  grid.sync();

  // ---------------- phase 2: attention (register-P flash) ----------------
  {
    const int vid = u;
    const int xcd = vid & 7, jj = vid >> 3;
    const int bh = xcd * 4 + (jj >> 4);
    const int qblk = jj & 15;

    const int n = bh >> 3, h = bh & 7;
    const int lane = tid & 63;
    const int col = lane & 31;        // q (and m) index
    const int hf = lane >> 5;         // lane half: k-slot group
    const int w = tid >> 6;
    const int qi = qblk * 128 + w * 32 + col;

    const short* Qh = wsS;
    const short* Kg = wsS + HEAD_ELEMS + (size_t)bh * Ln * DKv;      // [l][d]
    const short* Vg = wsS + 2 * HEAD_ELEMS + (size_t)bh * DKv * Ln;  // [d][l]

    // smem union: Ks[2] at 0 / 5120, Vs[2] at 10240 / 14592 (shorts)
    short8 aq[2];
#pragma unroll
    for (int c = 0; c < 2; ++c)
      aq[c] = *(const short8*)&Qh[(size_t)bh * Ln * DKv + (size_t)qi * DKv + c * 16 + hf * 8];

    short8 ones;
#pragma unroll
    for (int j = 0; j < 8; ++j) ones[j] = (short)0x3F80;  // bf16 1.0

    floatx16 o, ol;
#pragma unroll
    for (int i = 0; i < 16; ++i) { o[i] = 0.f; ol[i] = 0.f; }

    const int kg = tid >> 1, khalf = tid & 1;
    const int krow = (kg & ~12) | ((kg & 4) << 1) | ((kg & 8) >> 1);
    const int kst = krow * 40 + khalf * 16;
    const int vd = tid >> 3, vkb = tid & 7;
    const int vst = vd * 136 + vkb * 16;

    short8 kr0 = *(const short8*)(Kg + kg * 32 + khalf * 16);
    short8 kr1 = *(const short8*)(Kg + kg * 32 + khalf * 16 + 8);
    short8 vr0 = *(const short8*)(Vg + (size_t)vd * Ln + vkb * 16);
    short8 vr1 = *(const short8*)(Vg + (size_t)vd * Ln + vkb * 16 + 8);

    for (int kt = 0; kt < 16; ++kt) {
      short* ksb = smem + (kt & 1) * 5120;
      short* vsb = smem + 10240 + (kt & 1) * 4352;
      *(short8*)&ksb[kst] = kr0;
      *(short8*)&ksb[kst + 8] = kr1;
      *(short8*)&vsb[vst] = vr0;
      *(short8*)&vsb[vst + 8] = vr1;
      __syncthreads();
      if (kt < 15) {
        kr0 = *(const short8*)(Kg + (size_t)(kt + 1) * 4096 + kg * 32 + khalf * 16);
        kr1 = *(const short8*)(Kg + (size_t)(kt + 1) * 4096 + kg * 32 + khalf * 16 + 8);
        vr0 = *(const short8*)(Vg + (size_t)vd * Ln + (kt + 1) * 128 + vkb * 16);
        vr1 = *(const short8*)(Vg + (size_t)vd * Ln + (kt + 1) * 128 + vkb * 16 + 8);
      }

#pragma unroll
      for (int cc = 0; cc < 4; ++cc) {    // 32-key sub-chunks
        floatx16 st;
#pragma unroll
        for (int i = 0; i < 16; ++i) st[i] = 0.f;
        short8 kf0 = *(const short8*)&ksb[(cc * 32 + col) * 40 + hf * 8];
        short8 kf1 = *(const short8*)&ksb[(cc * 32 + col) * 40 + 16 + hf * 8];
        st = __builtin_amdgcn_mfma_f32_32x32x16_bf16(kf0, aq[0], st, 0, 0, 0);
        st = __builtin_amdgcn_mfma_f32_32x32x16_bf16(kf1, aq[1], st, 0, 0, 0);

        float p[16];
#pragma unroll
        for (int i = 0; i < 16; ++i) p[i] = __builtin_amdgcn_exp2f(st[i]);
        short8 pf[2];
#pragma unroll
        for (int half = 0; half < 2; ++half) {
          unsigned uu0 = __builtin_amdgcn_perm(
              __builtin_bit_cast(unsigned, p[half * 8 + 1]),
              __builtin_bit_cast(unsigned, p[half * 8 + 0]), 0x07060302u);
          unsigned uu1 = __builtin_amdgcn_perm(
              __builtin_bit_cast(unsigned, p[half * 8 + 3]),
              __builtin_bit_cast(unsigned, p[half * 8 + 2]), 0x07060302u);
          unsigned uu2 = __builtin_amdgcn_perm(
              __builtin_bit_cast(unsigned, p[half * 8 + 5]),
              __builtin_bit_cast(unsigned, p[half * 8 + 4]), 0x07060302u);
          unsigned uu3 = __builtin_amdgcn_perm(
              __builtin_bit_cast(unsigned, p[half * 8 + 7]),
              __builtin_bit_cast(unsigned, p[half * 8 + 6]), 0x07060302u);
          uint4 uu = make_uint4(uu0, uu1, uu2, uu3);
          pf[half] = __builtin_bit_cast(short8, uu);
        }

        ol = __builtin_amdgcn_mfma_f32_32x32x16_bf16(ones, pf[0], ol, 0, 0, 0);
        ol = __builtin_amdgcn_mfma_f32_32x32x16_bf16(ones, pf[1], ol, 0, 0, 0);

        short8 va0 = *(const short8*)&vsb[col * 136 + cc * 32 + hf * 8];
        short8 va1 = *(const short8*)&vsb[col * 136 + cc * 32 + 16 + hf * 8];
        o = __builtin_amdgcn_mfma_f32_32x32x16_bf16(va0, pf[0], o, 0, 0, 0);
        o = __builtin_amdgcn_mfma_f32_32x32x16_bf16(va1, pf[1], o, 0, 0, 0);
      }
    }

    const float inv = 1.f / ol[0];
    short* dst = &O2b[((size_t)n * Ln + qi) * INNER + h * DKv];
#pragma unroll
    for (int g4 = 0; g4 < 4; ++g4) {
      short4v pk = (short4v){f2bf(o[g4 * 4 + 0] * inv), f2bf(o[g4 * 4 + 1] * inv),
                             f2bf(o[g4 * 4 + 2] * inv), f2bf(o[g4 * 4 + 3] * inv)};
      *(short4v*)&dst[8 * g4 + 4 * hf] = pk;
    }
  }
  grid.sync();

  // ---------------- phase 3: fused FC + residual + LayerNorm ----------------
  {
    const int t0 = u * 16;
    const int col = tid & 15;
    const int quad = (tid & 63) >> 4;
    const int w = tid >> 6;

    short* As = smem;                       // 16*264 shorts
    float* sred = (float*)(smem + 4224);    // [2][16][4] floats

    {
      const int row = tid >> 4, k16 = tid & 15;
      *(short8*)&As[row * 264 + k16 * 16] =
          *(const short8*)&O2b[(size_t)(t0 + row) * INNER + k16 * 16];
      *(short8*)&As[row * 264 + k16 * 16 + 8] =
          *(const short8*)&O2b[(size_t)(t0 + row) * INNER + k16 * 16 + 8];
    }
    __syncthreads();

    const short* Wp = Wfcb + (size_t)(w * 128 + col) * INNER + quad * 8;

    floatx4 acc[8];
#pragma unroll
    for (int nj = 0; nj < 8; ++nj) acc[nj] = (floatx4){0.f, 0.f, 0.f, 0.f};

#pragma unroll
    for (int ks = 0; ks < 8; ++ks) {
      short8 a = *(const short8*)&As[col * 264 + ks * 32 + quad * 8];
#pragma unroll
      for (int nj = 0; nj < 8; ++nj) {
        short8 b = *(const short8*)&Wp[(size_t)nj * 16 * INNER + ks * 32];
        acc[nj] = __builtin_amdgcn_mfma_f32_16x16x32_bf16(a, b, acc[nj], 0, 0, 0);
      }
    }

    float s1[4], s2[4];
#pragma unroll
    for (int r = 0; r < 4; ++r) { s1[r] = 0.f; s2[r] = 0.f; }

#pragma unroll
    for (int nj = 0; nj < 8; ++nj) {
      const int c = w * 128 + nj * 16 + col;
      const float bi = bfc[c];
#pragma unroll
      for (int r = 0; r < 4; ++r) {
        const int t = t0 + quad * 4 + r;
        float x = acc[nj][r] + bi + q[(size_t)t * DM + c];
        acc[nj][r] = x;
        s1[r] += x;
        s2[r] += x * x;
      }
    }
#pragma unroll
    for (int r = 0; r < 4; ++r) {
#pragma unroll
      for (int off = 1; off <= 8; off <<= 1) {
        s1[r] += __shfl_xor(s1[r], off);
        s2[r] += __shfl_xor(s2[r], off);
      }
    }
    if (col == 0) {
#pragma unroll
      for (int r = 0; r < 4; ++r) {
        sred[(0 * 16 + quad * 4 + r) * 4 + w] = s1[r];
        sred[(1 * 16 + quad * 4 + r) * 4 + w] = s2[r];
      }
    }
    __syncthreads();

    float mean[4], rstd[4];
#pragma unroll
    for (int r = 0; r < 4; ++r) {
      const int tk = quad * 4 + r;
      const float S1 = sred[tk * 4 + 0] + sred[tk * 4 + 1] + sred[tk * 4 + 2] + sred[tk * 4 + 3];
      const float S2 = sred[(16 + tk) * 4 + 0] + sred[(16 + tk) * 4 + 1] +
                       sred[(16 + tk) * 4 + 2] + sred[(16 + tk) * 4 + 3];
      mean[r] = S1 * (1.f / 512.f);
      const float var = S2 * (1.f / 512.f) - mean[r] * mean[r];
      rstd[r] = rsqrtf(var + 1e-5f);
    }

#pragma unroll
    for (int nj = 0; nj < 8; ++nj) {
      const int c = w * 128 + nj * 16 + col;
      const float g = gamma[c], bb = beta[c];
#pragma unroll
      for (int r = 0; r < 4; ++r) {
        const int t = t0 + quad * 4 + r;
        outp[(size_t)t * DM + c] = g * (acc[nj][r] - mean[r]) * rstd[r] + bb;
      }
    }
  }
}

// ==================== Fallback path (previous 4-kernel pipeline) ====================
__global__ __launch_bounds__(256) void cvtw_kernel(
    const float* __restrict__ Wq, const float* __restrict__ Wk,
    const float* __restrict__ Wv, const float* __restrict__ Wfc,
    short* __restrict__ Wb, short* __restrict__ Wfcb)
{
  const int z = blockIdx.y;
  const float* src = z == 0 ? Wq : (z == 1 ? Wk : (z == 2 ? Wv : Wfc));
  short* dst = z < 3 ? Wb + (size_t)z * 131072 : Wfcb;
  const int idx = (blockIdx.x * 256 + threadIdx.x) * 4;
  float4 x = *(const float4*)&src[idx];
  *(short4v*)&dst[idx] = (short4v){f2bf(x.x), f2bf(x.y), f2bf(x.z), f2bf(x.w)};
}

__global__ __launch_bounds__(256) void proj_kernel(
    const float* __restrict__ q, const float* __restrict__ k, const float* __restrict__ v,
    const short* __restrict__ Wb,
    const float* __restrict__ bq, const float* __restrict__ bk,
    const float* __restrict__ bv,
    short* __restrict__ ws)
{
  const int mat = blockIdx.y;
  const float* X    = mat == 0 ? q  : (mat == 1 ? k  : v);
  const short* W    = Wb + (size_t)mat * 131072;
  const float* bias = mat == 0 ? bq : (mat == 1 ? bk : bv);
  short* outp = ws + (size_t)mat * HEAD_ELEMS;

  const int t0 = blockIdx.x * 64;
  const int tid = threadIdx.x;
  const int col = tid & 15;
  const int quad = (tid & 63) >> 4;
  const int w = tid >> 6;

  __shared__ short smem[23040];
  short* Xs  = smem;
  short* Wsh = smem + 64 * 72;

  floatx4 acc[16];
#pragma unroll
  for (int nj = 0; nj < 16; ++nj) acc[nj] = (floatx4){0.f, 0.f, 0.f, 0.f};

  float4 xr[4];
  short8 wr[8];
  auto loadX = [&](int k0) {
#pragma unroll
    for (int j = 0; j < 4; ++j) {
      const int i = tid + j * 256, row = i >> 4, c4 = i & 15;
      xr[j] = *(const float4*)&X[(size_t)(t0 + row) * DM + k0 + c4 * 4];
    }
  };
  auto loadW = [&](int k0) {
#pragma unroll
    for (int j = 0; j < 8; ++j) {
      const int s = tid + j * 256, jrow = s >> 3, c8 = s & 7;
      const int wrow = ((jrow & 31) << 3) + (jrow >> 5);
      wr[j] = *(const short8*)&W[(size_t)wrow * DM + k0 + c8 * 8];
    }
  };

  loadX(0);
  loadW(0);

  for (int kc = 0; kc < 8; ++kc) {
#pragma unroll
    for (int j = 0; j < 4; ++j) {
      const int i = tid + j * 256, row = i >> 4, c4 = i & 15;
      *(short4v*)&Xs[row * 72 + c4 * 4] =
          (short4v){f2bf(xr[j].x), f2bf(xr[j].y), f2bf(xr[j].z), f2bf(xr[j].w)};
    }
#pragma unroll
    for (int j = 0; j < 8; ++j) {
      const int s = tid + j * 256, jrow = s >> 3, c8 = s & 7;
      *(short8*)&Wsh[jrow * 72 + c8 * 8] = wr[j];
    }
    __syncthreads();
    if (kc < 7) {
      loadX((kc + 1) * 64);
      loadW((kc + 1) * 64);
    }
#pragma unroll
    for (int ks = 0; ks < 2; ++ks) {
      short8 a = *(const short8*)&Xs[(w * 16 + col) * 72 + ks * 32 + quad * 8];
#pragma unroll
      for (int nj = 0; nj < 16; ++nj) {
        short8 b = *(const short8*)&Wsh[(nj * 16 + col) * 72 + ks * 32 + quad * 8];
        acc[nj] = __builtin_amdgcn_mfma_f32_16x16x32_bf16(a, b, acc[nj], 0, 0, 0);
      }
    }
    __syncthreads();
  }

  short* Ct = smem;
  const int n = t0 >> 11, llb = t0 & (Ln - 1);

  if (mat < 2) {
#pragma unroll
    for (int nj = 0; nj < 16; ++nj) {
      const int j = nj * 16 + col;
      const int c = ((j & 31) << 3) + (j >> 5);
      const float bi = bias[c];
#pragma unroll
      for (int r = 0; r < 4; ++r) {
        float pv = acc[nj][r] + bi;
        if (mat == 0) pv *= C1;
        Ct[(w * 16 + quad * 4 + r) * 268 + j] = f2bf(pv);
      }
    }
    __syncthreads();
#pragma unroll
    for (int it = 0; it < 8; ++it) {
      const int cid = tid + it * 256;
      const int h = cid >> 8, tok = (cid >> 2) & 63, o = cid & 3;
      short8 val = *(const short8*)&Ct[tok * 268 + h * 32 + o * 8];
      *(short8*)&outp[((size_t)(n * NH + h) * Ln + llb + tok) * DKv + o * 8] = val;
    }
  } else {
#pragma unroll
    for (int nj = 0; nj < 16; ++nj) {
      const int j = nj * 16 + col;
      const int c = ((j & 31) << 3) + (j >> 5);
      const float bi = bias[c];
      short4v pk = (short4v){f2bf(acc[nj][0] + bi), f2bf(acc[nj][1] + bi),
                             f2bf(acc[nj][2] + bi), f2bf(acc[nj][3] + bi)};
      *(short4v*)&Ct[j * 72 + w * 16 + quad * 4] = pk;
    }
    __syncthreads();
#pragma unroll
    for (int it = 0; it < 8; ++it) {
      const int cid = tid + it * 256;
      const int j = cid >> 3, to = cid & 7;
      const int h = j >> 5, d = j & 31;
      short8 val = *(const short8*)&Ct[j * 72 + to * 8];
      *(short8*)&outp[((size_t)(n * NH + h) * DKv + d) * Ln + llb + to * 8] = val;
    }
  }
}

__global__ __launch_bounds__(256) void attn_kernel(const short* __restrict__ ws,
                                                   short* __restrict__ O2b)
{
  const int vid = blockIdx.x + 16 * blockIdx.y;
  const int xcd = vid & 7, jj = vid >> 3;
  const int bh = xcd * 4 + (jj >> 4);
  const int qblk = jj & 15;

  const int n = bh >> 3, h = bh & 7;
  const int tid = threadIdx.x;
  const int lane = tid & 63;
  const int col = lane & 31;
  const int hf = lane >> 5;
  const int w = tid >> 6;
  const int qi = qblk * 128 + w * 32 + col;

  const short* Qh = ws;
  const short* Kg = ws + HEAD_ELEMS + (size_t)bh * Ln * DKv;
  const short* Vg = ws + 2 * HEAD_ELEMS + (size_t)bh * DKv * Ln;

  __shared__ short Ks[2][128 * 40];
  __shared__ short Vs[2][32 * 136];

  short8 aq[2];
#pragma unroll
  for (int c = 0; c < 2; ++c)
    aq[c] = *(const short8*)&Qh[(size_t)bh * Ln * DKv + (size_t)qi * DKv + c * 16 + hf * 8];

  short8 ones;
#pragma unroll
  for (int j = 0; j < 8; ++j) ones[j] = (short)0x3F80;

  floatx16 o, ol;
#pragma unroll
  for (int i = 0; i < 16; ++i) { o[i] = 0.f; ol[i] = 0.f; }

  const int kg = tid >> 1, khalf = tid & 1;
  const int krow = (kg & ~12) | ((kg & 4) << 1) | ((kg & 8) >> 1);
  const int kst = krow * 40 + khalf * 16;
  const int vd = tid >> 3, vkb = tid & 7;
  const int vst = vd * 136 + vkb * 16;

  short8 kr0 = *(const short8*)(Kg + kg * 32 + khalf * 16);
  short8 kr1 = *(const short8*)(Kg + kg * 32 + khalf * 16 + 8);
  short8 vr0 = *(const short8*)(Vg + (size_t)vd * Ln + vkb * 16);
  short8 vr1 = *(const short8*)(Vg + (size_t)vd * Ln + vkb * 16 + 8);

  for (int kt = 0; kt < 16; ++kt) {
    short* ksb = Ks[kt & 1];
    short* vsb = Vs[kt & 1];
    *(short8*)&ksb[kst] = kr0;
    *(short8*)&ksb[kst + 8] = kr1;
    *(short8*)&vsb[vst] = vr0;
    *(short8*)&vsb[vst + 8] = vr1;
    __syncthreads();
    if (kt < 15) {
      kr0 = *(const short8*)(Kg + (size_t)(kt + 1) * 4096 + kg * 32 + khalf * 16);
      kr1 = *(const short8*)(Kg + (size_t)(kt + 1) * 4096 + kg * 32 + khalf * 16 + 8);
      vr0 = *(const short8*)(Vg + (size_t)vd * Ln + (kt + 1) * 128 + vkb * 16);
      vr1 = *(const short8*)(Vg + (size_t)vd * Ln + (kt + 1) * 128 + vkb * 16 + 8);
    }

#pragma unroll
    for (int cc = 0; cc < 4; ++cc) {
      floatx16 st;
#pragma unroll
      for (int i = 0; i < 16; ++i) st[i] = 0.f;
      short8 kf0 = *(const short8*)&ksb[(cc * 32 + col) * 40 + hf * 8];
      short8 kf1 = *(const short8*)&ksb[(cc * 32 + col) * 40 + 16 + hf * 8];
      st = __builtin_amdgcn_mfma_f32_32x32x16_bf16(kf0, aq[0], st, 0, 0, 0);
      st = __builtin_amdgcn_mfma_f32_32x32x16_bf16(kf1, aq[1], st, 0, 0, 0);

      float p[16];
#pragma unroll
      for (int i = 0; i < 16; ++i) p[i] = __builtin_amdgcn_exp2f(st[i]);
      short8 pf[2];
#pragma unroll
      for (int half = 0; half < 2; ++half) {
        unsigned uarr[4];
#pragma unroll
        for (int j = 0; j < 4; ++j)
          uarr[j] = __builtin_amdgcn_perm(
              __builtin_bit_cast(unsigned, p[half * 8 + 2 * j + 1]),
              __builtin_bit_cast(unsigned, p[half * 8 + 2 * j]), 0x07060302u);
        uint4 uu = make_uint4(uarr[0], uarr[1], uarr[2], uarr[3]);
        pf[half] = __builtin_bit_cast(short8, uu);
      }

      ol = __builtin_amdgcn_mfma_f32_32x32x16_bf16(ones, pf[0], ol, 0, 0, 0);
      ol = __builtin_amdgcn_mfma_f32_32x32x16_bf16(ones, pf[1], ol, 0, 0, 0);

      short8 va0 = *(const short8*)&vsb[col * 136 + cc * 32 + hf * 8];
      short8 va1 = *(const short8*)&vsb[col * 136 + cc * 32 + 16 + hf * 8];
      o = __builtin_amdgcn_mfma_f32_32x32x16_bf16(va0, pf[0], o, 0, 0, 0);
      o = __builtin_amdgcn_mfma_f32_32x32x16_bf16(va1, pf[1], o, 0, 0, 0);
    }
  }

  const float inv = 1.f / ol[0];
  short* dst = &O2b[((size_t)n * Ln + qi) * INNER + h * DKv];
#pragma unroll
  for (int g4 = 0; g4 < 4; ++g4) {
    short4v pk = (short4v){f2bf(o[g4 * 4 + 0] * inv), f2bf(o[g4 * 4 + 1] * inv),
                           f2bf(o[g4 * 4 + 2] * inv), f2bf(o[g4 * 4 + 3] * inv)};
    *(short4v*)&dst[8 * g4 + 4 * hf] = pk;
  }
}

__global__ __launch_bounds__(256) void fcln_kernel(
    const short* __restrict__ O2b, const short* __restrict__ Wfcb,
    const float* __restrict__ bfc, const float* __restrict__ qin,
    const float* __restrict__ gamma, const float* __restrict__ beta,
    float* __restrict__ outp)
{
  const int t0 = blockIdx.x * 16;
  const int tid = threadIdx.x;
  const int col = tid & 15;
  const int quad = (tid & 63) >> 4;
  const int w = tid >> 6;

  __shared__ short As[16 * 264];
  __shared__ float sred[2][16][4];

  {
    const int row = tid >> 4, k16 = tid & 15;
    *(short8*)&As[row * 264 + k16 * 16] =
        *(const short8*)&O2b[(size_t)(t0 + row) * INNER + k16 * 16];
    *(short8*)&As[row * 264 + k16 * 16 + 8] =
        *(const short8*)&O2b[(size_t)(t0 + row) * INNER + k16 * 16 + 8];
  }
  __syncthreads();

  const short* Wp = Wfcb + (size_t)(w * 128 + col) * INNER + quad * 8;

  floatx4 acc[8];
#pragma unroll
  for (int nj = 0; nj < 8; ++nj) acc[nj] = (floatx4){0.f, 0.f, 0.f, 0.f};

#pragma unroll
  for (int ks = 0; ks < 8; ++ks) {
    short8 a = *(const short8*)&As[col * 264 + ks * 32 + quad * 8];
#pragma unroll
    for (int nj = 0; nj < 8; ++nj) {
      short8 b = *(const short8*)&Wp[(size_t)nj * 16 * INNER + ks * 32];
      acc[nj] = __builtin_amdgcn_mfma_f32_16x16x32_bf16(a, b, acc[nj], 0, 0, 0);
    }
  }

  float s1[4], s2[4];
#pragma unroll
  for (int r = 0; r < 4; ++r) { s1[r] = 0.f; s2[r] = 0.f; }

#pragma unroll
  for (int nj = 0; nj < 8; ++nj) {
    const int c = w * 128 + nj * 16 + col;
    const float bi = bfc[c];
#pragma unroll
    for (int r = 0; r < 4; ++r) {
      const int t = t0 + quad * 4 + r;
      float x = acc[nj][r] + bi + qin[(size_t)t * DM + c];
      acc[nj][r] = x;
      s1[r] += x;
      s2[r] += x * x;
    }
  }
#pragma unroll
  for (int r = 0; r < 4; ++r) {
#pragma unroll
    for (int off = 1; off <= 8; off <<= 1) {
      s1[r] += __shfl_xor(s1[r], off);
      s2[r] += __shfl_xor(s2[r], off);
    }
  }
  if (col == 0) {
#pragma unroll
    for (int r = 0; r < 4; ++r) {
      sred[0][quad * 4 + r][w] = s1[r];
      sred[1][quad * 4 + r][w] = s2[r];
    }
  }
  __syncthreads();

  float mean[4], rstd[4];
#pragma unroll
  for (int r = 0; r < 4; ++r) {
    const int tk = quad * 4 + r;
    const float S1 = sred[0][tk][0] + sred[0][tk][1] + sred[0][tk][2] + sred[0][tk][3];
    const float S2 = sred[1][tk][0] + sred[1][tk][1] + sred[1][tk][2] + sred[1][tk][3];
    mean[r] = S1 * (1.f / 512.f);
    const float var = S2 * (1.f / 512.f) - mean[r] * mean[r];
    rstd[r] = rsqrtf(var + 1e-5f);
  }

#pragma unroll
  for (int nj = 0; nj < 8; ++nj) {
    const int c = w * 128 + nj * 16 + col;
    const float g = gamma[c], bb = beta[c];
#pragma unroll
    for (int r = 0; r < 4; ++r) {
      const int t = t0 + quad * 4 + r;
      outp[(size_t)t * DM + c] = g * (acc[nj][r] - mean[r]) * rstd[r] + bb;
    }
  }
}

extern "C" void kernel_launch(void* const* d_in, const int* in_sizes, int n_in,
                              void* d_out, int out_size, void* d_ws, size_t ws_size,
                              hipStream_t stream) {
  const float* q     = (const float*)d_in[0];
  const float* k     = (const float*)d_in[1];
  const float* v     = (const float*)d_in[2];
  const float* Wq    = (const float*)d_in[3];
  const float* bq    = (const float*)d_in[4];
  const float* Wk    = (const float*)d_in[5];
  const float* bk    = (const float*)d_in[6];
  const float* Wv    = (const float*)d_in[7];
  const float* bv    = (const float*)d_in[8];
  const float* Wfc   = (const float*)d_in[9];
  const float* bfc   = (const float*)d_in[10];
  const float* gamma = (const float*)d_in[11];
  const float* beta  = (const float*)d_in[12];

  short* wsS  = (short*)d_ws;
  short* O2b  = wsS + 3 * HEAD_ELEMS;
  short* Wb   = wsS + WB_OFF;
  short* Wfcb = wsS + WFCB_OFF;
  float* outP = (float*)d_out;

  void* kargs[] = {(void*)&q,  (void*)&k,  (void*)&v,
                   (void*)&Wq, (void*)&Wk, (void*)&Wv, (void*)&Wfc,
                   (void*)&bq, (void*)&bk, (void*)&bv, (void*)&bfc,
                   (void*)&gamma, (void*)&beta,
                   (void*)&wsS, (void*)&outP};
  hipError_t err = hipLaunchCooperativeKernel(
      reinterpret_cast<void*>(mega_kernel), dim3(512), dim3(256), kargs, 0, stream);

  if (err != hipSuccess) {               // fallback: proven 4-kernel pipeline
    (void)hipGetLastError();             // clear error state
    cvtw_kernel<<<dim3(128, 4), 256, 0, stream>>>(Wq, Wk, Wv, Wfc, Wb, Wfcb);
    dim3 gp(TTOK / 64, 3);
    proj_kernel<<<gp, 256, 0, stream>>>(q, k, v, Wb, bq, bk, bv, wsS);
    dim3 gatt(Ln / 128, Bn * NH);
    attn_kernel<<<gatt, 256, 0, stream>>>(wsS, O2b);
    fcln_kernel<<<dim3(TTOK / 16), 256, 0, stream>>>(O2b, Wfcb, bfc, q, gamma, beta,
                                                     outP);
  }
}

// Round 4
// 176.898 us; speedup vs baseline: 2.1060x; 2.1060x over previous
//
#include <hip/hip_runtime.h>
#include <math.h>

// Problem constants (fixed by reference)
constexpr int Bn = 4, Ln = 2048, DM = 512, NH = 8, DKv = 32, INNER = 256;
constexpr int TTOK = Bn * Ln;                              // 8192 tokens
constexpr size_t HEAD_ELEMS = (size_t)Bn * NH * Ln * DKv;  // 2,097,152 elems per Q/K/V

// Workspace layout (shorts):
//  [0,2M)   Qh bf16 [n,h,l,d]  (PRE-SCALED by log2(e)/sqrt(32))
//  [2M,4M)  Kh bf16 [n,h,l,d]
//  [4M,6M)  Vt bf16 [n,h,d,l]
//  [6M,8M)  O2b bf16 [tok][256]
//  [12.25M, +393216)  Wb bf16 (Wq|Wk|Wv)
//  [+131072]          Wfcb bf16

typedef short short8 __attribute__((ext_vector_type(8)));   // 8 bf16 (4 VGPRs)
typedef short short4v __attribute__((ext_vector_type(4)));  // 4 bf16 (2 VGPRs)
typedef float floatx4 __attribute__((ext_vector_type(4)));  // 16x16 MFMA C/D frag
typedef float floatx16 __attribute__((ext_vector_type(16))); // 32x32 MFMA C/D frag

constexpr size_t WB_OFF  = 12536832;                // shorts, 16B aligned
constexpr size_t WFCB_OFF = WB_OFF + 3 * 131072;

constexpr float C1 = 0.25505654f;  // log2(e)/sqrt(32), folded into Qh at projection

__device__ inline short f2bf(float x) {                     // RNE f32->bf16
  unsigned u = __builtin_bit_cast(unsigned, x);
  unsigned r = (u + 0x7FFFu + ((u >> 16) & 1u)) >> 16;
  return (short)r;
}

// ---------------- Weight pre-convert: fp32 -> bf16 ----------------
__global__ __launch_bounds__(256) void cvtw_kernel(
    const float* __restrict__ Wq, const float* __restrict__ Wk,
    const float* __restrict__ Wv, const float* __restrict__ Wfc,
    short* __restrict__ Wb, short* __restrict__ Wfcb)
{
  const int z = blockIdx.y;
  const float* src = z == 0 ? Wq : (z == 1 ? Wk : (z == 2 ? Wv : Wfc));
  short* dst = z < 3 ? Wb + (size_t)z * 131072 : Wfcb;
  const int idx = (blockIdx.x * 256 + threadIdx.x) * 4;   // 131072 elems, grid.x=128
  float4 x = *(const float4*)&src[idx];
  *(short4v*)&dst[idx] = (short4v){f2bf(x.x), f2bf(x.y), f2bf(x.z), f2bf(x.w)};
}

// ---------------- Projection (bf16 MFMA), occupancy-tiled ----------------
// grid (TTOK/64, 2, 3) = 768 blocks (3/CU, 12 waves/CU -- R3 counters showed the
// whole pipeline latency-bound at ~2 waves/SIMD; TLP is the lever, not traffic).
// Block = 64 tokens x 128 cols (half the heads: h in {4*hp .. 4*hp+3}).
// Internal col j in [0,128): h = 4*hp + (j>>5), d = j&31, physical W row = d*8+h.
// BK=64 chunks, reg prefetch, 2 barriers/chunk. Epilogue via LDS transpose,
// 16B/lane coalesced stores.
__global__ __launch_bounds__(256) void proj_kernel(
    const float* __restrict__ q, const float* __restrict__ k, const float* __restrict__ v,
    const short* __restrict__ Wb,
    const float* __restrict__ bq, const float* __restrict__ bk,
    const float* __restrict__ bv,
    short* __restrict__ ws)
{
  const int mat = blockIdx.z;
  const int hp  = blockIdx.y;               // heads 4hp .. 4hp+3
  const float* X    = mat == 0 ? q  : (mat == 1 ? k  : v);
  const short* W    = Wb + (size_t)mat * 131072;
  const float* bias = mat == 0 ? bq : (mat == 1 ? bk : bv);
  short* outp = ws + (size_t)mat * HEAD_ELEMS;

  const int t0 = blockIdx.x * 64;
  const int tid = threadIdx.x;
  const int col = tid & 15;
  const int quad = (tid & 63) >> 4;
  const int w = tid >> 6;

  __shared__ short smem[13824];           // 27.6 KB: Xs[64*72] | Wsh[128*72]
  short* Xs  = smem;
  short* Wsh = smem + 64 * 72;

  floatx4 acc[8];
#pragma unroll
  for (int nj = 0; nj < 8; ++nj) acc[nj] = (floatx4){0.f, 0.f, 0.f, 0.f};

  float4 xr[4];
  short8 wr[4];
  auto loadX = [&](int k0) {
#pragma unroll
    for (int j = 0; j < 4; ++j) {
      const int i = tid + j * 256, row = i >> 4, c4 = i & 15;
      xr[j] = *(const float4*)&X[(size_t)(t0 + row) * DM + k0 + c4 * 4];
    }
  };
  auto loadW = [&](int k0) {
#pragma unroll
    for (int j = 0; j < 4; ++j) {
      const int s = tid + j * 256, jrow = s >> 3, c8 = s & 7;
      const int wrow = ((jrow & 31) << 3) + 4 * hp + (jrow >> 5);
      wr[j] = *(const short8*)&W[(size_t)wrow * DM + k0 + c8 * 8];
    }
  };

  loadX(0);
  loadW(0);

  for (int kc = 0; kc < 8; ++kc) {
#pragma unroll
    for (int j = 0; j < 4; ++j) {
      const int i = tid + j * 256, row = i >> 4, c4 = i & 15;
      *(short4v*)&Xs[row * 72 + c4 * 4] =
          (short4v){f2bf(xr[j].x), f2bf(xr[j].y), f2bf(xr[j].z), f2bf(xr[j].w)};
    }
#pragma unroll
    for (int j = 0; j < 4; ++j) {
      const int s = tid + j * 256, jrow = s >> 3, c8 = s & 7;
      *(short8*)&Wsh[jrow * 72 + c8 * 8] = wr[j];
    }
    __syncthreads();
    if (kc < 7) {                       // prefetch next chunk while MFMAs run
      loadX((kc + 1) * 64);
      loadW((kc + 1) * 64);
    }
#pragma unroll
    for (int ks = 0; ks < 2; ++ks) {
      short8 a = *(const short8*)&Xs[(w * 16 + col) * 72 + ks * 32 + quad * 8];
#pragma unroll
      for (int nj = 0; nj < 8; ++nj) {
        short8 b = *(const short8*)&Wsh[(nj * 16 + col) * 72 + ks * 32 + quad * 8];
        acc[nj] = __builtin_amdgcn_mfma_f32_16x16x32_bf16(a, b, acc[nj], 0, 0, 0);
      }
    }
    __syncthreads();
  }

  // ---- epilogue: bias (+C1 for Q), LDS transpose, coalesced 16B stores ----
  short* Ct = smem;
  const int n = t0 >> 11, llb = t0 & (Ln - 1);

  if (mat < 2) {
    // Ct[t][j], pitch 136 (16B-aligned rows)
#pragma unroll
    for (int nj = 0; nj < 8; ++nj) {
      const int j = nj * 16 + col;
      const int c = ((j & 31) << 3) + 4 * hp + (j >> 5);
      const float bi = bias[c];
#pragma unroll
      for (int r = 0; r < 4; ++r) {
        float pv = acc[nj][r] + bi;
        if (mat == 0) pv *= C1;
        Ct[(w * 16 + quad * 4 + r) * 136 + j] = f2bf(pv);
      }
    }
    __syncthreads();
    // 1024 chunks: id = h_loc*256 + tok*4 + o ; per head a 4KB contiguous run
#pragma unroll
    for (int it = 0; it < 4; ++it) {
      const int cid = tid + it * 256;
      const int h_loc = cid >> 8, tok = (cid >> 2) & 63, o = cid & 3;
      short8 val = *(const short8*)&Ct[tok * 136 + h_loc * 32 + o * 8];
      const int h = 4 * hp + h_loc;
      *(short8*)&outp[((size_t)(n * NH + h) * Ln + llb + tok) * DKv + o * 8] = val;
    }
  } else {
    // CtV[j][t], pitch 72 (lane's 4 r-values are consecutive tokens -> b64 write)
#pragma unroll
    for (int nj = 0; nj < 8; ++nj) {
      const int j = nj * 16 + col;
      const int c = ((j & 31) << 3) + 4 * hp + (j >> 5);
      const float bi = bias[c];
      short4v pk = (short4v){f2bf(acc[nj][0] + bi), f2bf(acc[nj][1] + bi),
                             f2bf(acc[nj][2] + bi), f2bf(acc[nj][3] + bi)};
      *(short4v*)&Ct[j * 72 + w * 16 + quad * 4] = pk;
    }
    __syncthreads();
    // 1024 chunks: id = j*8 + to ; per (h,d): full 128B output line
#pragma unroll
    for (int it = 0; it < 4; ++it) {
      const int cid = tid + it * 256;
      const int j = cid >> 3, to = cid & 7;
      const int h = 4 * hp + (j >> 5), d = j & 31;
      short8 val = *(const short8*)&Ct[j * 72 + to * 8];
      *(short8*)&outp[((size_t)(n * NH + h) * DKv + d) * Ln + llb + to * 8] = val;
    }
  }
}

// ---------------- Attention: 32x32 MFMA register-P flash, split-K ----------------
// grid (32,32) = 1024 blocks (4/CU = 16 waves/CU; was 512 = 2 waves/SIMD, latency
// naked). Block 256 = 4 waves: wave w -> key-half g=w>>1 (keys g*1024..+1024),
// q-sub qs=w&1 (32 q each). p = exp2(st) has NO running max, so (o,l) partials
// are pure sums -> groups merge by addition through LDS at the end.
// l computed on VALU (15 adds/cc + one deferred shfl_xor(32)) instead of the
// ones-MFMA: frees 20 VGPRs to target 4 waves/SIMD.
// Per group: 8 chunks of 128 keys, single LDS buffer + reg prefetch.
__global__ __launch_bounds__(256) void attn_kernel(const short* __restrict__ ws,
                                                   short* __restrict__ O2b)
{
  // XCD-affine: all 32 q-blocks of a head share vid&7
  const int vid = blockIdx.x + 32 * blockIdx.y;
  const int xcd = vid & 7, jj = vid >> 3;
  const int bh = xcd * 4 + (jj >> 5);
  const int qblk = jj & 31;

  const int n = bh >> 3, h = bh & 7;
  const int tid = threadIdx.x;
  const int lane = tid & 63;
  const int col = lane & 31;        // q (and m) index
  const int hf = lane >> 5;         // lane half: k-slot group
  const int w = tid >> 6;
  const int g = w >> 1;             // key-half group
  const int qs = w & 1;
  const int qi = qblk * 64 + qs * 32 + col;
  const int kb0 = g * 1024;         // this group's key range base

  const short* Qh = ws;
  const short* Kg = ws + HEAD_ELEMS + (size_t)bh * Ln * DKv;      // [l][d]
  const short* Vg = ws + 2 * HEAD_ELEMS + (size_t)bh * DKv * Ln;  // [d][l]

  // per group: Ks 128*40 + Vs 32*136 = 9472 shorts; 2 groups = 37.9 KB
  __shared__ short smem[18944];
  short* ksb = smem + g * 9472;
  short* vsb = ksb + 5120;

  // Q as B-frags (pre-scaled by C1): B[k=d=c*16+8*hf+j][n=q=col]
  short8 aq[2];
#pragma unroll
  for (int c = 0; c < 2; ++c)
    aq[c] = *(const short8*)&Qh[(size_t)bh * Ln * DKv + (size_t)qi * DKv + c * 16 + hf * 8];

  floatx16 o;
#pragma unroll
  for (int i = 0; i < 16; ++i) o[i] = 0.f;
  float lacc = 0.f;

  // staging by this group's 128 threads
  const int gtid = tid & 127;
  // K: one key row per thread, permuted row (bits 2<->3 of key within 32-group)
  const int kg = gtid;
  const int krow = (kg & ~12) | ((kg & 4) << 1) | ((kg & 8) >> 1);
  // V: vd = row (0..31), vq = 32-key block (0..3)
  const int vd = gtid >> 2, vq = gtid & 3;

  short8 kr[4], vr[4];
  auto prefetch = [&](int kt) {
    const size_t kbase = (size_t)(kb0 + kt * 128);
#pragma unroll
    for (int s = 0; s < 4; ++s)
      kr[s] = *(const short8*)(Kg + (kbase + kg) * 32 + s * 8);
#pragma unroll
    for (int s = 0; s < 4; ++s)
      vr[s] = *(const short8*)(Vg + (size_t)vd * Ln + kbase + vq * 32 + s * 8);
  };

  prefetch(0);

  for (int kt = 0; kt < 8; ++kt) {
#pragma unroll
    for (int s = 0; s < 4; ++s) *(short8*)&ksb[krow * 40 + s * 8] = kr[s];
#pragma unroll
    for (int s = 0; s < 4; ++s) *(short8*)&vsb[vd * 136 + vq * 32 + s * 8] = vr[s];
    __syncthreads();
    if (kt < 7) prefetch(kt + 1);   // reg prefetch overlaps compute

#pragma unroll
    for (int cc = 0; cc < 4; ++cc) {    // 32-key sub-chunks
      // St = K·Q^T  (A rows = permuted-key LDS rows; contraction over d=32)
      floatx16 st;
#pragma unroll
      for (int i = 0; i < 16; ++i) st[i] = 0.f;
      short8 kf0 = *(const short8*)&ksb[(cc * 32 + col) * 40 + hf * 8];
      short8 kf1 = *(const short8*)&ksb[(cc * 32 + col) * 40 + 16 + hf * 8];
      st = __builtin_amdgcn_mfma_f32_32x32x16_bf16(kf0, aq[0], st, 0, 0, 0);
      st = __builtin_amdgcn_mfma_f32_32x32x16_bf16(kf1, aq[1], st, 0, 0, 0);

      // p = exp2(st) (already log2-scaled); pack regs 0..7 / 8..15 -> B-frags
      float p[16];
#pragma unroll
      for (int i = 0; i < 16; ++i) p[i] = __builtin_amdgcn_exp2f(st[i]);

      // l partial on VALU (rows split across hf; merged by shfl_xor(32) at end)
      float ls = 0.f;
#pragma unroll
      for (int i = 0; i < 16; ++i) ls += p[i];
      lacc += ls;

      short8 pf[2];
#pragma unroll
      for (int half = 0; half < 2; ++half) {
        unsigned u0 = __builtin_amdgcn_perm(
            __builtin_bit_cast(unsigned, p[half * 8 + 1]),
            __builtin_bit_cast(unsigned, p[half * 8 + 0]), 0x07060302u);
        unsigned u1 = __builtin_amdgcn_perm(
            __builtin_bit_cast(unsigned, p[half * 8 + 3]),
            __builtin_bit_cast(unsigned, p[half * 8 + 2]), 0x07060302u);
        unsigned u2 = __builtin_amdgcn_perm(
            __builtin_bit_cast(unsigned, p[half * 8 + 5]),
            __builtin_bit_cast(unsigned, p[half * 8 + 4]), 0x07060302u);
        unsigned u3 = __builtin_amdgcn_perm(
            __builtin_bit_cast(unsigned, p[half * 8 + 7]),
            __builtin_bit_cast(unsigned, p[half * 8 + 6]), 0x07060302u);
        uint4 uu = make_uint4(u0, u1, u2, u3);
        pf[half] = __builtin_bit_cast(short8, uu);
      }

      // O^T += V^T · P  (A = V natural order: keys cc*32 + 16*half + 8*hf + j)
      short8 va0 = *(const short8*)&vsb[col * 136 + cc * 32 + hf * 8];
      short8 va1 = *(const short8*)&vsb[col * 136 + cc * 32 + 16 + hf * 8];
      o = __builtin_amdgcn_mfma_f32_32x32x16_bf16(va0, pf[0], o, 0, 0, 0);
      o = __builtin_amdgcn_mfma_f32_32x32x16_bf16(va1, pf[1], o, 0, 0, 0);
    }
    __syncthreads();                 // protect LDS before next chunk's store
  }

  // ---- merge key-half groups (pure sums), normalize, store ----
  float* red = (float*)smem;         // 128 x 17 floats = 8.7 KB (stride 17: no conflicts)
  if (tid >= 128) {
    const int idx = tid - 128;
#pragma unroll
    for (int i = 0; i < 16; ++i) red[idx * 17 + i] = o[i];
    red[idx * 17 + 16] = lacc;
  }
  __syncthreads();
  if (tid < 128) {
#pragma unroll
    for (int i = 0; i < 16; ++i) o[i] += red[tid * 17 + i];
    lacc += red[tid * 17 + 16];
    const float ltot = lacc + __shfl_xor(lacc, 32);   // merge hf halves
    const float inv = 1.f / ltot;
    short* dst = &O2b[((size_t)n * Ln + qi) * INNER + h * DKv];
#pragma unroll
    for (int g4 = 0; g4 < 4; ++g4) {  // regs 4g4..4g4+3 -> d = 8*g4 + 4*hf + (0..3)
      short4v pk = (short4v){f2bf(o[g4 * 4 + 0] * inv), f2bf(o[g4 * 4 + 1] * inv),
                             f2bf(o[g4 * 4 + 2] * inv), f2bf(o[g4 * 4 + 3] * inv)};
      *(short4v*)&dst[8 * g4 + 4 * hf] = pk;
    }
  }
}

// ---------------- Fused FC + residual + LayerNorm -> fp32 out ----------------
// grid (TTOK/16) = 512 blocks x 512 threads = 8 waves (16 waves/CU; was 4 waves).
// Block = 16 tokens x 512 cols; wave w owns cols [w*64, w*64+64). A staged in LDS;
// W B-frags straight from global (Wfcb 256KB L2-resident). x kept fp32.
__global__ __launch_bounds__(512) void fcln_kernel(
    const short* __restrict__ O2b, const short* __restrict__ Wfcb,
    const float* __restrict__ bfc, const float* __restrict__ qin,
    const float* __restrict__ gamma, const float* __restrict__ beta,
    float* __restrict__ outp)
{
  const int t0 = blockIdx.x * 16;
  const int tid = threadIdx.x;
  const int col = tid & 15;
  const int quad = (tid & 63) >> 4;
  const int w = tid >> 6;            // 0..7

  __shared__ short As[16 * 264];
  __shared__ float sred[2][16][8];

  {
    const int row = tid >> 5, k8 = tid & 31;      // 512 threads: 1 short8 each
    *(short8*)&As[row * 264 + k8 * 8] =
        *(const short8*)&O2b[(size_t)(t0 + row) * INNER + k8 * 8];
  }
  __syncthreads();

  const short* Wp = Wfcb + (size_t)(w * 64 + col) * INNER + quad * 8;

  floatx4 acc[4];
#pragma unroll
  for (int nj = 0; nj < 4; ++nj) acc[nj] = (floatx4){0.f, 0.f, 0.f, 0.f};

#pragma unroll
  for (int ks = 0; ks < 8; ++ks) {
    short8 a = *(const short8*)&As[col * 264 + ks * 32 + quad * 8];
#pragma unroll
    for (int nj = 0; nj < 4; ++nj) {
      short8 b = *(const short8*)&Wp[(size_t)nj * 16 * INNER + ks * 32];
      acc[nj] = __builtin_amdgcn_mfma_f32_16x16x32_bf16(a, b, acc[nj], 0, 0, 0);
    }
  }

  // x = acc + bias + residual (fp32), accumulate per-token partial sums
  float s1[4], s2[4];
#pragma unroll
  for (int r = 0; r < 4; ++r) { s1[r] = 0.f; s2[r] = 0.f; }

#pragma unroll
  for (int nj = 0; nj < 4; ++nj) {
    const int c = w * 64 + nj * 16 + col;
    const float bi = bfc[c];
#pragma unroll
    for (int r = 0; r < 4; ++r) {
      const int t = t0 + quad * 4 + r;
      float x = acc[nj][r] + bi + qin[(size_t)t * DM + c];
      acc[nj][r] = x;
      s1[r] += x;
      s2[r] += x * x;
    }
  }
  // reduce across the 16 lanes of this quad group
#pragma unroll
  for (int r = 0; r < 4; ++r) {
#pragma unroll
    for (int off = 1; off <= 8; off <<= 1) {
      s1[r] += __shfl_xor(s1[r], off);
      s2[r] += __shfl_xor(s2[r], off);
    }
  }
  if (col == 0) {
#pragma unroll
    for (int r = 0; r < 4; ++r) {
      sred[0][quad * 4 + r][w] = s1[r];
      sred[1][quad * 4 + r][w] = s2[r];
    }
  }
  __syncthreads();

  float mean[4], rstd[4];
#pragma unroll
  for (int r = 0; r < 4; ++r) {
    const int tk = quad * 4 + r;
    float S1 = 0.f, S2 = 0.f;
#pragma unroll
    for (int ww = 0; ww < 8; ++ww) { S1 += sred[0][tk][ww]; S2 += sred[1][tk][ww]; }
    mean[r] = S1 * (1.f / 512.f);
    const float var = S2 * (1.f / 512.f) - mean[r] * mean[r];
    rstd[r] = rsqrtf(var + 1e-5f);
  }

#pragma unroll
  for (int nj = 0; nj < 4; ++nj) {
    const int c = w * 64 + nj * 16 + col;
    const float g = gamma[c], bb = beta[c];
#pragma unroll
    for (int r = 0; r < 4; ++r) {
      const int t = t0 + quad * 4 + r;
      outp[(size_t)t * DM + c] = g * (acc[nj][r] - mean[r]) * rstd[r] + bb;
    }
  }
}

extern "C" void kernel_launch(void* const* d_in, const int* in_sizes, int n_in,
                              void* d_out, int out_size, void* d_ws, size_t ws_size,
                              hipStream_t stream) {
  const float* q     = (const float*)d_in[0];
  const float* k     = (const float*)d_in[1];
  const float* v     = (const float*)d_in[2];
  const float* Wq    = (const float*)d_in[3];
  const float* bq    = (const float*)d_in[4];
  const float* Wk    = (const float*)d_in[5];
  const float* bk    = (const float*)d_in[6];
  const float* Wv    = (const float*)d_in[7];
  const float* bv    = (const float*)d_in[8];
  const float* Wfc   = (const float*)d_in[9];
  const float* bfc   = (const float*)d_in[10];
  const float* gamma = (const float*)d_in[11];
  const float* beta  = (const float*)d_in[12];

  short* wsS  = (short*)d_ws;
  short* O2b  = wsS + 3 * HEAD_ELEMS;
  short* Wb   = wsS + WB_OFF;
  short* Wfcb = wsS + WFCB_OFF;

  cvtw_kernel<<<dim3(128, 4), 256, 0, stream>>>(Wq, Wk, Wv, Wfc, Wb, Wfcb);

  dim3 gp(TTOK / 64, 2, 3);
  proj_kernel<<<gp, 256, 0, stream>>>(q, k, v, Wb, bq, bk, bv, wsS);

  dim3 gatt(32, 32);
  attn_kernel<<<gatt, 256, 0, stream>>>(wsS, O2b);

  fcln_kernel<<<dim3(TTOK / 16), 512, 0, stream>>>(O2b, Wfcb, bfc, q, gamma, beta,
                                                   (float*)d_out);
}